// Round 1
// 313.725 us; speedup vs baseline: 1.0265x; 1.0265x over previous
//
#include <hip/hip_runtime.h>

#define BS 256
#define NQ 512
#define NC 128
#define NP 256
#define NG 128
#define TQ 32
#define PTS (NC + 1)   // padded predAct tile stride: bank = (qo + aid) % 32, conflict-free gather
#define BIGC 1.0e6f
#define EPSC 1e-6f

// ws layout (floats):
//   [0, BS*NP)                 : lse per (b,p)
//   [BS*NP, +BS*8*2*NQ)        : per-slab partials [b][slab8][2][NQ]
//     [..][0][q] = sum_p P , [..][1][q] = sum_p log1p(-Pc)

// ---------------- K1: lse + per-q totals, one pass over att ----------------
// 512 thr, 16 lanes/row, 32 rows (one slab) per block, 8 slabs per batch.
__global__ __launch_bounds__(512) void pre_kernel(const float* __restrict__ att,
                                                  float* __restrict__ lse,
                                                  float* __restrict__ part) {
    __shared__ float attS[32 * NQ];   // exp(v - rowmax), 64 KB
    __shared__ float invS[32];        // 1/rowsum
    const int t   = threadIdx.x;
    const int blk = blockIdx.x;       // b*8 + slab
    const int b   = blk >> 3;
    const int r   = t >> 4;           // row 0..31
    const int p   = (blk & 7) * 32 + r;
    const int sub = t & 15;

    const float4* a4 = (const float4*)(att + ((size_t)(b * NP + p)) * NQ);
    float4 v[8];
#pragma unroll
    for (int i = 0; i < 8; ++i) v[i] = a4[sub + 16 * i];

    float mx = -1e30f;
#pragma unroll
    for (int i = 0; i < 8; ++i)
        mx = fmaxf(mx, fmaxf(fmaxf(v[i].x, v[i].y), fmaxf(v[i].z, v[i].w)));
#pragma unroll
    for (int off = 1; off < 16; off <<= 1) mx = fmaxf(mx, __shfl_xor(mx, off, 64));

    float s = 0.f;
#pragma unroll
    for (int i = 0; i < 8; ++i) {
        v[i].x = __expf(v[i].x - mx); v[i].y = __expf(v[i].y - mx);
        v[i].z = __expf(v[i].z - mx); v[i].w = __expf(v[i].w - mx);
        s += v[i].x + v[i].y + v[i].z + v[i].w;
        *(float4*)(attS + r * NQ + 4 * sub + 64 * i) = v[i];
    }
#pragma unroll
    for (int off = 1; off < 16; off <<= 1) s += __shfl_xor(s, off, 64);
    if (sub == 0) {
        invS[r] = 1.f / s;
        lse[b * NP + p] = mx + __logf(s);
    }
    __syncthreads();

    // pass 2: thread t owns column q=t; plain conflict-free LDS reads, no atomics
    float sz = 0.f, sl = 0.f;
#pragma unroll 8
    for (int pp = 0; pp < 32; ++pp) {
        const float P = attS[pp * NQ + t] * invS[pp];
        sz += P;
        const float c = fminf(fmaxf(P, EPSC), 1.f - EPSC);
        sl += __logf(1.f - c);
    }
    float* basep = part + (size_t)blk * 2 * NQ;
    basep[t]      = sz;
    basep[NQ + t] = sl;
}

// ---------------- K2: cost for a (b, 32-query) tile; 512 threads ----------------
// LDS = 54272 B -> 3 blocks/CU (24 waves). Divisors pre-folded into a single
// w array: w[rank][q] = -x/m + log1p(-Pc)/nm, so phase C sums ONE array and
// grp = sum_members(w) - sl/nm. Activity gather moved to a padded LDS tile.
__global__ __launch_bounds__(512, 6) void cost_kernel(
    const float* __restrict__ predAct,   // [BS,NQ,NC]
    const float* __restrict__ att,       // [BS,NP,NQ]
    const int*   __restrict__ actIds,    // [BS,NG]
    const int*   __restrict__ grpIds,    // [BS,NP]
    const float* __restrict__ lseAtt,    // [BS*NP]
    const float* __restrict__ part,      // [BS][8][2][NQ]
    float*       __restrict__ out)       // [BS,NQ,NG]
{
    __shared__ float wS[NP * TQ];        // 32 KB: fused member contribution, CSR-permuted rows
    __shared__ float pTile[TQ * PTS];    // 16.1 KB: predAct tile, stride 129 (conflict-free gather)
    __shared__ float lseS[NP];
    __shared__ float lseAct[TQ];
    __shared__ float szG[TQ], slG[TQ];
    __shared__ int   gidS[NP];
    __shared__ int   rankS[NP];
    __shared__ int   aidS[NG];
    __shared__ int   cntS[NG];
    __shared__ int   startS[NG];

    const int b  = blockIdx.x >> 4;
    const int q0 = (blockIdx.x & 15) * TQ;
    const int t  = threadIdx.x;

    // prefetch att tile (4 x float4) — consumed in phase A after CSR build
    const int pr  = t >> 3;              // 64 rows per iteration
    const int qo4 = (t & 7) * 4;
    float4 v[4];
#pragma unroll
    for (int it = 0; it < 4; ++it)
        v[it] = *(const float4*)(att + ((size_t)(b * NP + it * 64 + pr)) * NQ + q0 + qo4);

    // prefetch predAct rows (wave wv owns rows wv+8k); reused for BOTH the
    // activity LSE reduction and the LDS gather tile
    const int wv = t >> 6, ln = t & 63;
    float pa0[4], pa1[4];
#pragma unroll
    for (int k = 0; k < 4; ++k) {
        const float* rowp = predAct + ((size_t)(b * NQ + q0 + wv + 8 * k)) * NC;
        pa0[k] = rowp[ln]; pa1[k] = rowp[ln + 64];
    }

    // small staging
    if (t < NP) { lseS[t] = lseAtt[b * NP + t]; gidS[t] = grpIds[b * NP + t]; }
    if (t < NG) { aidS[t] = actIds[b * NG + t]; cntS[t] = 0; }
    if (t < 2 * TQ) {   // per-q totals from K1 partials
        const int qo = t & 31, which = t >> 5;
        const float* pb = part + ((size_t)(b * 8)) * 2 * NQ + (size_t)which * NQ + q0 + qo;
        float s = 0.f;
#pragma unroll
        for (int k = 0; k < 8; ++k) s += pb[(size_t)k * 2 * NQ];
        if (which == 0) szG[qo] = s; else slG[qo] = s;
    }
    __syncthreads();

    int myPos = 0;
    if (t < NP) myPos = atomicAdd(&cntS[gidS[t]], 1);
    __syncthreads();

    // single-wave exclusive scan of group counts (lane owns 2 adjacent groups)
    if (t < 64) {
        const int c0 = cntS[2 * t], c1 = cntS[2 * t + 1];
        const int ps = c0 + c1;
        int s = ps;
#pragma unroll
        for (int off = 1; off < 64; off <<= 1) {
            const int w = __shfl_up(s, off, 64);
            if (t >= off) s += w;
        }
        startS[2 * t]     = s - ps;
        startS[2 * t + 1] = s - ps + c0;
    }
    __syncthreads();
    if (t < NP) rankS[t] = startS[gidS[t]] + myPos;
    __syncthreads();

    // phase A: fused w tile at permuted rank (transcendentals happen HERE).
    // m,nm known per-row already -> fold 1/m and 1/nm into the stored value.
    #pragma unroll
    for (int it = 0; it < 4; ++it) {
        const int p  = it * 64 + pr;
        const float l = lseS[p];
        const int rr = rankS[p];
        const int m  = cntS[gidS[p]];
        const float im  = 1.f / (float)m;                       // m >= 1: p is a member
        const float inm = 1.f / fmaxf((float)(NP - m), 1.f);    // safe_nm like the reference
        float w[4];
        const float vv[4] = {v[it].x, v[it].y, v[it].z, v[it].w};
#pragma unroll
        for (int j = 0; j < 4; ++j) {
            const float x = vv[j] - l;                          // logP
            const float e = __expf(x);
            const float c = fminf(fmaxf(e, EPSC), 1.f - EPSC);
            const float ll = __logf(1.f - c);                   // log1p(-Pc)
            w[j] = ll * inm - x * im;
        }
        *(float4*)(wS + rr * TQ + qo4) = *(float4*)w;
    }

    // phase A2: activity row LSEs (one wave per row, 4 rows/wave) + stage tile
#pragma unroll
    for (int k = 0; k < 4; ++k) {
        const int r = wv + 8 * k;
        float mx = fmaxf(pa0[k], pa1[k]);
#pragma unroll
        for (int off = 1; off < 64; off <<= 1) mx = fmaxf(mx, __shfl_xor(mx, off, 64));
        float s = __expf(pa0[k] - mx) + __expf(pa1[k] - mx);
#pragma unroll
        for (int off = 1; off < 64; off <<= 1) s += __shfl_xor(s, off, 64);
        if (ln == 0) lseAct[r] = mx + __logf(s);
        pTile[r * PTS + ln]      = pa0[k];   // bank (r+ln)%32: 2-way max, free
        pTile[r * PTS + 64 + ln] = pa1[k];
    }
    __syncthreads();

    // phase C: single-array gather; member rows sequential in LDS
#pragma unroll
    for (int rep = 0; rep < 2; ++rep) {
        const int idx = rep * 512 + t;
        const int qo  = idx & 31;          // lane-fast -> conflict-free banks
        const int g4  = (idx >> 5) * 4;
        const float sl = slG[qo], pz = szG[qo], la = lseAct[qo];
        float res[4];
#pragma unroll
        for (int j = 0; j < 4; ++j) {
            const int g  = g4 + j;
            const int m  = cntS[g];
            const int st = startS[g];
            float s = 0.f;
            for (int i = 0; i < m; ++i) s += wS[(st + i) * TQ + qo];
            const float mf  = (float)m;
            const float nmf = fmaxf((float)(NP - m), 1.f);
            float grp = s - sl / nmf;      // = -ms/m - (sl-ml)/nm
            float szc = fabsf(pz - mf) * (1.f / (float)NP);
            if (m == 0) { grp = BIGC; szc = BIGC; }
            const float av = pTile[qo * PTS + aidS[g]];   // LDS gather, conflict-free
            res[j] = grp + (la - av) + szc;
        }
        *(float4*)(out + ((size_t)(b * NQ + q0 + qo)) * NG + g4) = *(float4*)res;
    }
}

extern "C" void kernel_launch(void* const* d_in, const int* in_sizes, int n_in,
                              void* d_out, int out_size, void* d_ws, size_t ws_size,
                              hipStream_t stream) {
    const float* predAct = (const float*)d_in[0];
    const float* att     = (const float*)d_in[1];
    const int*   actIds  = (const int*)d_in[2];
    const int*   grpIds  = (const int*)d_in[3];
    float*       out     = (float*)d_out;
    float*       lse     = (float*)d_ws;
    float*       part    = lse + (size_t)BS * NP;

    pre_kernel<<<BS * 8, 512, 0, stream>>>(att, lse, part);
    cost_kernel<<<BS * (NQ / TQ), 512, 0, stream>>>(predAct, att, actIds, grpIds, lse, part, out);
}

// Round 2
// 299.276 us; speedup vs baseline: 1.0761x; 1.0483x over previous
//
#include <hip/hip_runtime.h>

#define BS 256
#define NQ 512
#define NC 128
#define NP 256
#define NG 128
#define TQ 32
#define PTS (NC + 1)   // padded predAct tile stride: bank = (qo + aid) % 32, conflict-free gather
#define BIGC 1.0e6f
#define EPSC 1e-6f

// ws layout (floats):
//   [0, BS*NP)                 : lse per (b,p)
//   [BS*NP, +BS*8*2*NQ)        : per-slab partials [b][slab8][2][NQ]
//     [..][0][q] = sum_p P , [..][1][q] = sum_p log1p(-Pc)

// ---------------- K1: lse + per-q totals, one pass over att ----------------
// 512 thr, 16 lanes/row, 32 rows (one slab) per block, 8 slabs per batch.
// LDS halved to 32 KB (two 16-row halves) -> 4 blocks/CU (was 2).
__global__ __launch_bounds__(512, 8) void pre_kernel(const float* __restrict__ att,
                                                     float* __restrict__ lse,
                                                     float* __restrict__ part) {
    __shared__ float attS[16 * NQ];   // P values, 32 KB (half slab at a time)
    const int t   = threadIdx.x;
    const int blk = blockIdx.x;       // b*8 + slab
    const int b   = blk >> 3;
    const int r   = t >> 4;           // row 0..31
    const int p   = (blk & 7) * 32 + r;
    const int sub = t & 15;

    const float4* a4 = (const float4*)(att + ((size_t)(b * NP + p)) * NQ);
    float4 v[8];
#pragma unroll
    for (int i = 0; i < 8; ++i) v[i] = a4[sub + 16 * i];

    float mx = -1e30f;
#pragma unroll
    for (int i = 0; i < 8; ++i)
        mx = fmaxf(mx, fmaxf(fmaxf(v[i].x, v[i].y), fmaxf(v[i].z, v[i].w)));
#pragma unroll
    for (int off = 1; off < 16; off <<= 1) mx = fmaxf(mx, __shfl_xor(mx, off, 64));

    float s = 0.f;
#pragma unroll
    for (int i = 0; i < 8; ++i) {
        v[i].x = __expf(v[i].x - mx); v[i].y = __expf(v[i].y - mx);
        v[i].z = __expf(v[i].z - mx); v[i].w = __expf(v[i].w - mx);
        s += v[i].x + v[i].y + v[i].z + v[i].w;
    }
#pragma unroll
    for (int off = 1; off < 16; off <<= 1) s += __shfl_xor(s, off, 64);
    const float inv = 1.f / s;
    if (sub == 0) lse[b * NP + p] = mx + __logf(s);
    // fold 1/rowsum into the stored values -> LDS holds P directly
#pragma unroll
    for (int i = 0; i < 8; ++i) {
        v[i].x *= inv; v[i].y *= inv; v[i].z *= inv; v[i].w *= inv;
    }

    float sz = 0.f, sl = 0.f;
    // half 0: rows 0..15
    if (r < 16) {
#pragma unroll
        for (int i = 0; i < 8; ++i)
            *(float4*)(attS + r * NQ + 4 * sub + 64 * i) = v[i];
    }
    __syncthreads();
#pragma unroll
    for (int pp = 0; pp < 16; ++pp) {
        const float P = attS[pp * NQ + t];
        sz += P;
        const float c = fminf(fmaxf(P, EPSC), 1.f - EPSC);
        sl += __logf(1.f - c);
    }
    __syncthreads();
    // half 1: rows 16..31
    if (r >= 16) {
#pragma unroll
        for (int i = 0; i < 8; ++i)
            *(float4*)(attS + (r - 16) * NQ + 4 * sub + 64 * i) = v[i];
    }
    __syncthreads();
#pragma unroll
    for (int pp = 0; pp < 16; ++pp) {
        const float P = attS[pp * NQ + t];
        sz += P;
        const float c = fminf(fmaxf(P, EPSC), 1.f - EPSC);
        sl += __logf(1.f - c);
    }

    float* basep = part + (size_t)blk * 2 * NQ;
    basep[t]      = sz;
    basep[NQ + t] = sl;
}

// ---------------- K2: cost for a (b, 32-query) tile; 512 threads ----------------
// Phase C rewritten as prefix-sum segment lookup: member-sum of group g =
// cum[start+m] - cum[start], both static ds_reads. No runtime-trip loops.
// LDS = 52864 B. cntS packs start|m<<16; scratch packs lseS/gid->rank|m<<16,
// then is reused as the scan chunk-total buffer.
__global__ __launch_bounds__(512, 6) void cost_kernel(
    const float* __restrict__ predAct,   // [BS,NQ,NC]
    const float* __restrict__ att,       // [BS,NP,NQ]
    const int*   __restrict__ actIds,    // [BS,NG]
    const int*   __restrict__ grpIds,    // [BS,NP]
    const float* __restrict__ lseAtt,    // [BS*NP]
    const float* __restrict__ part,      // [BS][8][2][NQ]
    float*       __restrict__ out)       // [BS,NQ,NG]
{
    __shared__ float wS[(NP + 1) * TQ];  // 32.9 KB: fused member w, CSR rows; becomes excl. prefix
    __shared__ float pTile[TQ * PTS];    // 16.1 KB: predAct tile, stride 129 (conflict-free gather)
    __shared__ float scratch[512];       // [0,256): lseS ; [256,512): gid->rank|m<<16 ; reused as scanP[16][32]
    __shared__ float lseAct[TQ];
    __shared__ float szG[TQ], slG[TQ];
    __shared__ int   aidS[NG];
    __shared__ int   cntS[NG];           // atomic counters -> packed start|m<<16

    float* lseS  = scratch;
    int*   prS   = (int*)(scratch + 256);
    float* scanP = scratch;              // alive only after lseS/prS are dead

    const int b  = blockIdx.x >> 4;
    const int q0 = (blockIdx.x & 15) * TQ;
    const int t  = threadIdx.x;

    // prefetch att tile (4 x float4) — consumed in phase A after CSR build
    const int pr  = t >> 3;              // 64 rows per iteration
    const int qo4 = (t & 7) * 4;
    float4 v[4];
#pragma unroll
    for (int it = 0; it < 4; ++it)
        v[it] = *(const float4*)(att + ((size_t)(b * NP + it * 64 + pr)) * NQ + q0 + qo4);

    // prefetch predAct rows (wave wv owns rows wv+8k); reused for BOTH the
    // activity LSE reduction and the LDS gather tile
    const int wv = t >> 6, ln = t & 63;
    float pa0[4], pa1[4];
#pragma unroll
    for (int k = 0; k < 4; ++k) {
        const float* rowp = predAct + ((size_t)(b * NQ + q0 + wv + 8 * k)) * NC;
        pa0[k] = rowp[ln]; pa1[k] = rowp[ln + 64];
    }

    // small staging
    if (t < NP) { lseS[t] = lseAtt[b * NP + t]; prS[t] = grpIds[b * NP + t]; }
    if (t < NG) { aidS[t] = actIds[b * NG + t]; cntS[t] = 0; }
    if (t < 2 * TQ) {   // per-q totals from K1 partials
        const int qo = t & 31, which = t >> 5;
        const float* pb = part + ((size_t)(b * 8)) * 2 * NQ + (size_t)which * NQ + q0 + qo;
        float s = 0.f;
#pragma unroll
        for (int k = 0; k < 8; ++k) s += pb[(size_t)k * 2 * NQ];
        if (which == 0) szG[qo] = s; else slG[qo] = s;
    }
    __syncthreads();

    int myPos = 0;
    if (t < NP) myPos = atomicAdd(&cntS[prS[t]], 1);
    __syncthreads();

    // single-wave exclusive scan of group counts (lane owns 2 adjacent groups);
    // result written back packed: start | m<<16
    if (t < 64) {
        const int c0 = cntS[2 * t], c1 = cntS[2 * t + 1];
        const int ps = c0 + c1;
        int s = ps;
#pragma unroll
        for (int off = 1; off < 64; off <<= 1) {
            const int w = __shfl_up(s, off, 64);
            if (t >= off) s += w;
        }
        const int e = s - ps;
        cntS[2 * t]     = e | (c0 << 16);
        cntS[2 * t + 1] = (e + c0) | (c1 << 16);
    }
    __syncthreads();
    if (t < NP) {
        const int g  = prS[t];
        const int cs = cntS[g];
        prS[t] = ((cs & 0xffff) + myPos) | (cs & 0xffff0000);   // rank | m<<16
    }
    __syncthreads();

    // phase A: fused w tile at permuted rank (transcendentals happen HERE).
    // w = log1p(-Pc)/nm - logP/m  -> member-sum(w) - sl/nm == grouping cost
#pragma unroll
    for (int it = 0; it < 4; ++it) {
        const int p  = it * 64 + pr;
        const float l = lseS[p];
        const int pk = prS[p];
        const int rr = pk & 0xffff;
        const int m  = pk >> 16;
        const float im  = 1.f / (float)m;                       // m >= 1: p is a member
        const float inm = 1.f / fmaxf((float)(NP - m), 1.f);    // safe_nm like the reference
        float w[4];
        const float vv[4] = {v[it].x, v[it].y, v[it].z, v[it].w};
#pragma unroll
        for (int j = 0; j < 4; ++j) {
            const float x = vv[j] - l;                          // logP
            const float e = __expf(x);
            const float c = fminf(fmaxf(e, EPSC), 1.f - EPSC);
            const float ll = __logf(1.f - c);                   // log1p(-Pc)
            w[j] = ll * inm - x * im;
        }
        *(float4*)(wS + rr * TQ + qo4) = *(float4*)w;
    }

    // phase A2: activity row LSEs (one wave per row, 4 rows/wave) + stage tile
#pragma unroll
    for (int k = 0; k < 4; ++k) {
        const int r = wv + 8 * k;
        float mx = fmaxf(pa0[k], pa1[k]);
#pragma unroll
        for (int off = 1; off < 64; off <<= 1) mx = fmaxf(mx, __shfl_xor(mx, off, 64));
        float s = __expf(pa0[k] - mx) + __expf(pa1[k] - mx);
#pragma unroll
        for (int off = 1; off < 64; off <<= 1) s += __shfl_xor(s, off, 64);
        if (ln == 0) lseAct[r] = mx + __logf(s);
        pTile[r * PTS + ln]      = pa0[k];   // bank (r+ln)%32: 2-way max, free
        pTile[r * PTS + 64 + ln] = pa1[k];
    }
    __syncthreads();   // wS complete; lseS/prS dead from here -> scanP may reuse scratch

    // phase B: column-wise exclusive prefix over the 256 CSR rows (+ total row).
    // 16 threads per column, 16 rows each. All static, conflict-free.
    {
        const int cq = t & 31;          // column
        const int ck = t >> 5;          // chunk 0..15
        float pv[16];
        float run = 0.f;
#pragma unroll
        for (int i = 0; i < 16; ++i) {
            pv[i] = run;
            run += wS[(16 * ck + i) * TQ + cq];
        }
        scanP[ck * 32 + cq] = run;      // bank = cq: conflict-free write
        __syncthreads();
        float offs = 0.f;
#pragma unroll
        for (int j = 0; j < 15; ++j)
            if (j < ck) offs += scanP[j * 32 + cq];   // broadcast reads
#pragma unroll
        for (int i = 0; i < 16; ++i)
            wS[(16 * ck + i) * TQ + cq] = offs + pv[i];
        if (ck == 15) wS[NP * TQ + cq] = offs + run;  // grand total row
    }
    __syncthreads();

    // phase C: segment sums via two prefix lookups; no loops, no divergence
#pragma unroll
    for (int rep = 0; rep < 2; ++rep) {
        const int idx = rep * 512 + t;
        const int qo  = idx & 31;          // lane-fast -> conflict-free banks
        const int g4  = (idx >> 5) * 4;
        const float sl = slG[qo], pz = szG[qo], la = lseAct[qo];
        float res[4];
#pragma unroll
        for (int j = 0; j < 4; ++j) {
            const int g  = g4 + j;
            const int cs = cntS[g];
            const int m  = cs >> 16;
            const int st = cs & 0xffff;
            const float ms = wS[(st + m) * TQ + qo] - wS[st * TQ + qo];
            const float mf  = (float)m;
            const float nmf = fmaxf((float)(NP - m), 1.f);
            float grp = ms - sl / nmf;     // = -mem/m - (sl-ml)/nm
            float szc = fabsf(pz - mf) * (1.f / (float)NP);
            if (m == 0) { grp = BIGC; szc = BIGC; }
            const float av = pTile[qo * PTS + aidS[g]];   // LDS gather, conflict-free
            res[j] = grp + (la - av) + szc;
        }
        *(float4*)(out + ((size_t)(b * NQ + q0 + qo)) * NG + g4) = *(float4*)res;
    }
}

extern "C" void kernel_launch(void* const* d_in, const int* in_sizes, int n_in,
                              void* d_out, int out_size, void* d_ws, size_t ws_size,
                              hipStream_t stream) {
    const float* predAct = (const float*)d_in[0];
    const float* att     = (const float*)d_in[1];
    const int*   actIds  = (const int*)d_in[2];
    const int*   grpIds  = (const int*)d_in[3];
    float*       out     = (float*)d_out;
    float*       lse     = (float*)d_ws;
    float*       part    = lse + (size_t)BS * NP;

    pre_kernel<<<BS * 8, 512, 0, stream>>>(att, lse, part);
    cost_kernel<<<BS * (NQ / TQ), 512, 0, stream>>>(predAct, att, actIds, grpIds, lse, part, out);
}

// Round 3
// 293.174 us; speedup vs baseline: 1.0985x; 1.0208x over previous
//
#include <hip/hip_runtime.h>

#define BS 256
#define NQ 512
#define NC 128
#define NP 256
#define NG 128
#define TQ 32
#define PTS (NC + 1)   // padded predAct tile stride: bank = (qo + aid) % 32, conflict-free gather
#define BIGC 1.0e6f
#define EPSC 1e-6f

// ws layout (floats):
//   [0, BS*NP)                 : lse per (b,p)
//   [BS*NP, +BS*8*2*NQ)        : per-slab partials [b][slab8][2][NQ]
//     [..][0][q] = sum_p P , [..][1][q] = sum_p log1p(-Pc)

// ---------------- K1: lse + per-q totals, one pass over att ----------------
// 512 thr, 16 lanes/row, 32 rows (one slab) per block, 8 slabs per batch.
// LDS 32 KB (two 16-row halves) -> 4 blocks/CU.
__global__ __launch_bounds__(512, 8) void pre_kernel(const float* __restrict__ att,
                                                     float* __restrict__ lse,
                                                     float* __restrict__ part) {
    __shared__ float attS[16 * NQ];   // P values, 32 KB (half slab at a time)
    const int t   = threadIdx.x;
    const int blk = blockIdx.x;       // b*8 + slab
    const int b   = blk >> 3;
    const int r   = t >> 4;           // row 0..31
    const int p   = (blk & 7) * 32 + r;
    const int sub = t & 15;

    const float4* a4 = (const float4*)(att + ((size_t)(b * NP + p)) * NQ);
    float4 v[8];
#pragma unroll
    for (int i = 0; i < 8; ++i) v[i] = a4[sub + 16 * i];

    float mx = -1e30f;
#pragma unroll
    for (int i = 0; i < 8; ++i)
        mx = fmaxf(mx, fmaxf(fmaxf(v[i].x, v[i].y), fmaxf(v[i].z, v[i].w)));
#pragma unroll
    for (int off = 1; off < 16; off <<= 1) mx = fmaxf(mx, __shfl_xor(mx, off, 64));

    float s = 0.f;
#pragma unroll
    for (int i = 0; i < 8; ++i) {
        v[i].x = __expf(v[i].x - mx); v[i].y = __expf(v[i].y - mx);
        v[i].z = __expf(v[i].z - mx); v[i].w = __expf(v[i].w - mx);
        s += v[i].x + v[i].y + v[i].z + v[i].w;
    }
#pragma unroll
    for (int off = 1; off < 16; off <<= 1) s += __shfl_xor(s, off, 64);
    const float inv = 1.f / s;
    if (sub == 0) lse[b * NP + p] = mx + __logf(s);
    // fold 1/rowsum into the stored values -> LDS holds P directly
#pragma unroll
    for (int i = 0; i < 8; ++i) {
        v[i].x *= inv; v[i].y *= inv; v[i].z *= inv; v[i].w *= inv;
    }

    float sz = 0.f, sl = 0.f;
    // half 0: rows 0..15
    if (r < 16) {
#pragma unroll
        for (int i = 0; i < 8; ++i)
            *(float4*)(attS + r * NQ + 4 * sub + 64 * i) = v[i];
    }
    __syncthreads();
#pragma unroll
    for (int pp = 0; pp < 16; ++pp) {
        const float P = attS[pp * NQ + t];
        sz += P;
        const float c = fminf(fmaxf(P, EPSC), 1.f - EPSC);
        sl += __logf(1.f - c);
    }
    __syncthreads();
    // half 1: rows 16..31
    if (r >= 16) {
#pragma unroll
        for (int i = 0; i < 8; ++i)
            *(float4*)(attS + (r - 16) * NQ + 4 * sub + 64 * i) = v[i];
    }
    __syncthreads();
#pragma unroll
    for (int pp = 0; pp < 16; ++pp) {
        const float P = attS[pp * NQ + t];
        sz += P;
        const float c = fminf(fmaxf(P, EPSC), 1.f - EPSC);
        sl += __logf(1.f - c);
    }

    float* basep = part + (size_t)blk * 2 * NQ;
    basep[t]      = sz;
    basep[NQ + t] = sl;
}

// ---------------- K2: cost for a (b, 32-query) tile; 512 threads ----------------
// Member-sum via exclusive prefix over CSR-permuted wS: cum[st+m]-cum[st].
// Phase C split in two so the predAct tile REUSES the wS storage -> LDS
// 36352 B -> 4 blocks/CU (32 waves, 100% cap). pa rows ride in registers
// from the prologue prefetch to the late tile fill.
__global__ __launch_bounds__(512, 8) void cost_kernel(
    const float* __restrict__ predAct,   // [BS,NQ,NC]
    const float* __restrict__ att,       // [BS,NP,NQ]
    const int*   __restrict__ actIds,    // [BS,NG]
    const int*   __restrict__ grpIds,    // [BS,NP]
    const float* __restrict__ lseAtt,    // [BS*NP]
    const float* __restrict__ part,      // [BS][8][2][NQ]
    float*       __restrict__ out)       // [BS,NQ,NG]
{
    __shared__ float wS[(NP + 1) * TQ];  // 32.9 KB: w tile -> prefix -> REUSED as predAct tile
    __shared__ float scratch[512];       // [0,256): lseS ; [256,512): rank|m<<16 ; then scanP[16][32]
    __shared__ float lseAct[TQ];
    __shared__ float szG[TQ], slG[TQ];
    __shared__ int   aidS[NG];
    __shared__ int   cntS[NG];           // atomic counters -> packed start|m<<16

    float* lseS  = scratch;
    int*   prS   = (int*)(scratch + 256);
    float* scanP = scratch;              // alive only after lseS/prS are dead
    float* pTile = wS;                   // alive only after the prefix is consumed (32*PTS = 4128 floats)

    const int b  = blockIdx.x >> 4;
    const int q0 = (blockIdx.x & 15) * TQ;
    const int t  = threadIdx.x;

    // prefetch att tile (4 x float4) — consumed in phase A after CSR build
    const int pr  = t >> 3;              // 64 rows per iteration
    const int qo4 = (t & 7) * 4;
    float4 v[4];
#pragma unroll
    for (int it = 0; it < 4; ++it)
        v[it] = *(const float4*)(att + ((size_t)(b * NP + it * 64 + pr)) * NQ + q0 + qo4);

    // prefetch predAct rows (wave wv owns rows wv+8k); used for the activity
    // LSEs (phase A2) and the late LDS gather tile (phase C2)
    const int wv = t >> 6, ln = t & 63;
    float pa0[4], pa1[4];
#pragma unroll
    for (int k = 0; k < 4; ++k) {
        const float* rowp = predAct + ((size_t)(b * NQ + q0 + wv + 8 * k)) * NC;
        pa0[k] = rowp[ln]; pa1[k] = rowp[ln + 64];
    }

    // small staging
    if (t < NP) { lseS[t] = lseAtt[b * NP + t]; prS[t] = grpIds[b * NP + t]; }
    if (t < NG) { aidS[t] = actIds[b * NG + t]; cntS[t] = 0; }
    if (t < 2 * TQ) {   // per-q totals from K1 partials
        const int qo = t & 31, which = t >> 5;
        const float* pb = part + ((size_t)(b * 8)) * 2 * NQ + (size_t)which * NQ + q0 + qo;
        float s = 0.f;
#pragma unroll
        for (int k = 0; k < 8; ++k) s += pb[(size_t)k * 2 * NQ];
        if (which == 0) szG[qo] = s; else slG[qo] = s;
    }
    __syncthreads();

    int myPos = 0;
    if (t < NP) myPos = atomicAdd(&cntS[prS[t]], 1);
    __syncthreads();

    // single-wave exclusive scan of group counts (lane owns 2 adjacent groups);
    // result written back packed: start | m<<16
    if (t < 64) {
        const int c0 = cntS[2 * t], c1 = cntS[2 * t + 1];
        const int ps = c0 + c1;
        int s = ps;
#pragma unroll
        for (int off = 1; off < 64; off <<= 1) {
            const int w = __shfl_up(s, off, 64);
            if (t >= off) s += w;
        }
        const int e = s - ps;
        cntS[2 * t]     = e | (c0 << 16);
        cntS[2 * t + 1] = (e + c0) | (c1 << 16);
    }
    __syncthreads();
    if (t < NP) {
        const int g  = prS[t];
        const int cs = cntS[g];
        prS[t] = ((cs & 0xffff) + myPos) | (cs & 0xffff0000);   // rank | m<<16
    }
    __syncthreads();

    // phase A: fused w tile at permuted rank (transcendentals happen HERE).
    // w = log1p(-Pc)/nm - logP/m  -> member-sum(w) - sl/nm == grouping cost
#pragma unroll
    for (int it = 0; it < 4; ++it) {
        const int p  = it * 64 + pr;
        const float l = lseS[p];
        const int pk = prS[p];
        const int rr = pk & 0xffff;
        const int m  = pk >> 16;
        const float im  = 1.f / (float)m;                       // m >= 1: p is a member
        const float inm = 1.f / fmaxf((float)(NP - m), 1.f);    // safe_nm like the reference
        float w[4];
        const float vv[4] = {v[it].x, v[it].y, v[it].z, v[it].w};
#pragma unroll
        for (int j = 0; j < 4; ++j) {
            const float x = vv[j] - l;                          // logP
            const float e = __expf(x);
            const float c = fminf(fmaxf(e, EPSC), 1.f - EPSC);
            const float ll = __logf(1.f - c);                   // log1p(-Pc)
            w[j] = ll * inm - x * im;
        }
        *(float4*)(wS + rr * TQ + qo4) = *(float4*)w;
    }

    // phase A2: activity row LSEs (one wave per row, 4 rows/wave)
#pragma unroll
    for (int k = 0; k < 4; ++k) {
        const int r = wv + 8 * k;
        float mx = fmaxf(pa0[k], pa1[k]);
#pragma unroll
        for (int off = 1; off < 64; off <<= 1) mx = fmaxf(mx, __shfl_xor(mx, off, 64));
        float s = __expf(pa0[k] - mx) + __expf(pa1[k] - mx);
#pragma unroll
        for (int off = 1; off < 64; off <<= 1) s += __shfl_xor(s, off, 64);
        if (ln == 0) lseAct[r] = mx + __logf(s);
    }
    __syncthreads();   // wS complete; lseS/prS dead from here -> scanP may reuse scratch

    // phase B: column-wise exclusive prefix over the 256 CSR rows (+ total row).
    // 16 threads per column, 16 rows each. All static, conflict-free.
    {
        const int cq = t & 31;          // column
        const int ck = t >> 5;          // chunk 0..15
        float pv[16];
        float run = 0.f;
#pragma unroll
        for (int i = 0; i < 16; ++i) {
            pv[i] = run;
            run += wS[(16 * ck + i) * TQ + cq];
        }
        scanP[ck * 32 + cq] = run;      // bank = cq: conflict-free write
        __syncthreads();
        float offs = 0.f;
#pragma unroll
        for (int j = 0; j < 15; ++j)
            if (j < ck) offs += scanP[j * 32 + cq];   // broadcast reads
#pragma unroll
        for (int i = 0; i < 16; ++i)
            wS[(16 * ck + i) * TQ + cq] = offs + pv[i];
        if (ck == 15) wS[NP * TQ + cq] = offs + run;  // grand total row
    }
    __syncthreads();

    // phase C1: grp + size cost for all 8 outputs into registers (prefix lookups)
    const int qoC = t & 31;             // lane-fast -> conflict-free banks
    const int g4A = (t >> 5) * 4;       // rep 0 groups
    const int g4B = g4A + 64;           // rep 1 groups
    float resA[4], resB[4];
    {
        const float sl = slG[qoC], pz = szG[qoC];
#pragma unroll
        for (int rep = 0; rep < 2; ++rep) {
            float* res = rep ? resB : resA;
            const int g4 = rep ? g4B : g4A;
#pragma unroll
            for (int j = 0; j < 4; ++j) {
                const int g  = g4 + j;
                const int cs = cntS[g];
                const int m  = cs >> 16;
                const int st = cs & 0xffff;
                const float ms = wS[(st + m) * TQ + qoC] - wS[st * TQ + qoC];
                const float mf  = (float)m;
                const float nmf = fmaxf((float)(NP - m), 1.f);
                float grp = ms - sl / nmf;     // = -mem/m - (sl-ml)/nm
                float szc = fabsf(pz - mf) * (1.f / (float)NP);
                if (m == 0) { grp = BIGC; szc = BIGC; }
                res[j] = grp + szc;
            }
        }
    }
    __syncthreads();   // all prefix reads done -> wS storage may be reused

    // phase C2: fill predAct tile into the wS region (stride 129, conflict-free)
#pragma unroll
    for (int k = 0; k < 4; ++k) {
        const int r = wv + 8 * k;
        pTile[r * PTS + ln]      = pa0[k];   // bank (r+ln)%32: 2-way max, free
        pTile[r * PTS + 64 + ln] = pa1[k];
    }
    __syncthreads();

    // phase C3: activity term + store
    {
        const float la = lseAct[qoC];
#pragma unroll
        for (int rep = 0; rep < 2; ++rep) {
            float* res = rep ? resB : resA;
            const int g4 = rep ? g4B : g4A;
#pragma unroll
            for (int j = 0; j < 4; ++j) {
                const float av = pTile[qoC * PTS + aidS[g4 + j]];   // LDS gather, conflict-free
                res[j] += la - av;
            }
            *(float4*)(out + ((size_t)(b * NQ + q0 + qoC)) * NG + g4) = *(float4*)res;
        }
    }
}

extern "C" void kernel_launch(void* const* d_in, const int* in_sizes, int n_in,
                              void* d_out, int out_size, void* d_ws, size_t ws_size,
                              hipStream_t stream) {
    const float* predAct = (const float*)d_in[0];
    const float* att     = (const float*)d_in[1];
    const int*   actIds  = (const int*)d_in[2];
    const int*   grpIds  = (const int*)d_in[3];
    float*       out     = (float*)d_out;
    float*       lse     = (float*)d_ws;
    float*       part    = lse + (size_t)BS * NP;

    pre_kernel<<<BS * 8, 512, 0, stream>>>(att, lse, part);
    cost_kernel<<<BS * (NQ / TQ), 512, 0, stream>>>(predAct, att, actIds, grpIds, lse, part, out);
}

// Round 4
// 282.901 us; speedup vs baseline: 1.1384x; 1.0363x over previous
//
#include <hip/hip_runtime.h>

#define BS 256
#define NQ 512
#define NC 128
#define NP 256
#define NG 128
#define TQ 32
#define PTS (NC + 1)   // padded predAct tile stride: bank = (qo + aid) % 32, conflict-free gather
#define BIGC 1.0e6f
#define EPSC 1e-6f

// ws layout (floats): [0, BS*NP) : lse per (b,p).  (per-q partials now live in K2)

// ---------------- K1: pure row LSE; one wave per person-row ----------------
// 8 rows/block, no LDS, no barriers. 134 MB streaming read + 256 KB write.
__global__ __launch_bounds__(512, 8) void lse_kernel(const float* __restrict__ att,
                                                     float* __restrict__ lse) {
    const int t   = threadIdx.x;
    const int wv  = t >> 6, ln = t & 63;
    const int row = blockIdx.x * 8 + wv;          // global b*NP + p
    const float4* a4 = (const float4*)(att + (size_t)row * NQ);
    const float4 v0 = a4[2 * ln];
    const float4 v1 = a4[2 * ln + 1];

    float mx = fmaxf(fmaxf(fmaxf(v0.x, v0.y), fmaxf(v0.z, v0.w)),
                     fmaxf(fmaxf(v1.x, v1.y), fmaxf(v1.z, v1.w)));
#pragma unroll
    for (int off = 1; off < 64; off <<= 1) mx = fmaxf(mx, __shfl_xor(mx, off, 64));

    float s = __expf(v0.x - mx) + __expf(v0.y - mx) + __expf(v0.z - mx) + __expf(v0.w - mx)
            + __expf(v1.x - mx) + __expf(v1.y - mx) + __expf(v1.z - mx) + __expf(v1.w - mx);
#pragma unroll
    for (int off = 1; off < 64; off <<= 1) s += __shfl_xor(s, off, 64);

    if (ln == 0) lse[row] = mx + __logf(s);
}

// ---------------- K2: cost for a (b, 32-query) tile; 512 threads ----------------
// Member-sum via exclusive prefix over CSR-permuted wS: cum[st+m]-cum[st].
// Per-q totals (sz = sum_p P, sl = sum_p log1p(-Pc)) are column sums of the
// values phase A already computes -> reduced in-kernel (shfl + 2 KB redS),
// no second att pass anywhere. LDS 38400 B -> 4 blocks/CU.
__global__ __launch_bounds__(512, 8) void cost_kernel(
    const float* __restrict__ predAct,   // [BS,NQ,NC]
    const float* __restrict__ att,       // [BS,NP,NQ]
    const int*   __restrict__ actIds,    // [BS,NG]
    const int*   __restrict__ grpIds,    // [BS,NP]
    const float* __restrict__ lseAtt,    // [BS*NP]
    float*       __restrict__ out)       // [BS,NQ,NG]
{
    __shared__ float wS[(NP + 1) * TQ];  // 32.9 KB: w tile -> prefix -> REUSED as predAct tile
    __shared__ float scratch[512];       // [0,256): lseS ; [256,512): rank|m<<16 ; then scanP[16][32]
    __shared__ float redS[512];          // [0,256): per-wave P col-sums ; [256,512): ll col-sums
    __shared__ float lseAct[TQ];
    __shared__ float szG[TQ], slG[TQ];
    __shared__ int   aidS[NG];
    __shared__ int   cntS[NG];           // atomic counters -> packed start|m<<16

    float* lseS  = scratch;
    int*   prS   = (int*)(scratch + 256);
    float* scanP = scratch;              // alive only after lseS/prS are dead
    float* pTile = wS;                   // alive only after the prefix is consumed

    const int b  = blockIdx.x >> 4;
    const int q0 = (blockIdx.x & 15) * TQ;
    const int t  = threadIdx.x;

    // prefetch att tile (4 x float4) — consumed in phase A after CSR build
    const int pr  = t >> 3;              // 64 rows per iteration
    const int qo4 = (t & 7) * 4;
    float4 v[4];
#pragma unroll
    for (int it = 0; it < 4; ++it)
        v[it] = *(const float4*)(att + ((size_t)(b * NP + it * 64 + pr)) * NQ + q0 + qo4);

    // prefetch predAct rows (wave wv owns rows wv+8k); used for the activity
    // LSEs (phase A2) and the late LDS gather tile (phase C2)
    const int wv = t >> 6, ln = t & 63;
    float pa0[4], pa1[4];
#pragma unroll
    for (int k = 0; k < 4; ++k) {
        const float* rowp = predAct + ((size_t)(b * NQ + q0 + wv + 8 * k)) * NC;
        pa0[k] = rowp[ln]; pa1[k] = rowp[ln + 64];
    }

    // small staging
    if (t < NP) { lseS[t] = lseAtt[b * NP + t]; prS[t] = grpIds[b * NP + t]; }
    if (t < NG) { aidS[t] = actIds[b * NG + t]; cntS[t] = 0; }
    __syncthreads();

    int myPos = 0;
    if (t < NP) myPos = atomicAdd(&cntS[prS[t]], 1);
    __syncthreads();

    // single-wave exclusive scan of group counts (lane owns 2 adjacent groups);
    // result written back packed: start | m<<16
    if (t < 64) {
        const int c0 = cntS[2 * t], c1 = cntS[2 * t + 1];
        const int ps = c0 + c1;
        int s = ps;
#pragma unroll
        for (int off = 1; off < 64; off <<= 1) {
            const int w = __shfl_up(s, off, 64);
            if (t >= off) s += w;
        }
        const int e = s - ps;
        cntS[2 * t]     = e | (c0 << 16);
        cntS[2 * t + 1] = (e + c0) | (c1 << 16);
    }
    __syncthreads();
    if (t < NP) {
        const int g  = prS[t];
        const int cs = cntS[g];
        prS[t] = ((cs & 0xffff) + myPos) | (cs & 0xffff0000);   // rank | m<<16
    }
    __syncthreads();

    // phase A: fused w tile at permuted rank (transcendentals happen HERE).
    // w = log1p(-Pc)/nm - logP/m ; simultaneously accumulate the per-q column
    // sums of P and log1p(-Pc) for the size/nonmember terms.
    float szL[4] = {0.f, 0.f, 0.f, 0.f}, slL[4] = {0.f, 0.f, 0.f, 0.f};
#pragma unroll
    for (int it = 0; it < 4; ++it) {
        const int p  = it * 64 + pr;
        const float l = lseS[p];
        const int pk = prS[p];
        const int rr = pk & 0xffff;
        const int m  = pk >> 16;
        const float im  = 1.f / (float)m;                       // m >= 1: p is a member
        const float inm = 1.f / fmaxf((float)(NP - m), 1.f);    // safe_nm like the reference
        float w[4];
        const float vv[4] = {v[it].x, v[it].y, v[it].z, v[it].w};
#pragma unroll
        for (int j = 0; j < 4; ++j) {
            const float x = vv[j] - l;                          // logP
            const float e = __expf(x);                          // P
            const float c = fminf(fmaxf(e, EPSC), 1.f - EPSC);
            const float ll = __logf(1.f - c);                   // log1p(-Pc)
            szL[j] += e;
            slL[j] += ll;
            w[j] = ll * inm - x * im;
        }
        *(float4*)(wS + rr * TQ + qo4) = *(float4*)w;
    }
    // reduce column sums over the wave's 8 sub-rows (lanes stride 8)
#pragma unroll
    for (int j = 0; j < 4; ++j) {
#pragma unroll
        for (int off = 8; off < 64; off <<= 1) {
            szL[j] += __shfl_xor(szL[j], off, 64);
            slL[j] += __shfl_xor(slL[j], off, 64);
        }
    }
    if (ln < 8) {   // lane ln owns columns qo = 4*ln..4*ln+3
        *(float4*)(redS + wv * 32 + ln * 4)       = *(float4*)szL;
        *(float4*)(redS + 256 + wv * 32 + ln * 4) = *(float4*)slL;
    }

    // phase A2: activity row LSEs (one wave per row, 4 rows/wave)
#pragma unroll
    for (int k = 0; k < 4; ++k) {
        const int r = wv + 8 * k;
        float mx = fmaxf(pa0[k], pa1[k]);
#pragma unroll
        for (int off = 1; off < 64; off <<= 1) mx = fmaxf(mx, __shfl_xor(mx, off, 64));
        float s = __expf(pa0[k] - mx) + __expf(pa1[k] - mx);
#pragma unroll
        for (int off = 1; off < 64; off <<= 1) s += __shfl_xor(s, off, 64);
        if (ln == 0) lseAct[r] = mx + __logf(s);
    }
    __syncthreads();   // wS + redS complete; lseS/prS dead -> scanP may reuse scratch

    // cross-wave column-sum finish (8 values each, broadcast-friendly banks)
    if (t < 64) {
        const int q = t & 31, which = t >> 5;
        const float* rb = redS + which * 256 + q;
        float s = 0.f;
#pragma unroll
        for (int w8 = 0; w8 < 8; ++w8) s += rb[w8 * 32];
        if (which == 0) szG[q] = s; else slG[q] = s;
    }

    // phase B: column-wise exclusive prefix over the 256 CSR rows (+ total row).
    // 16 threads per column, 16 rows each. All static, conflict-free.
    {
        const int cq = t & 31;          // column
        const int ck = t >> 5;          // chunk 0..15
        float pv[16];
        float run = 0.f;
#pragma unroll
        for (int i = 0; i < 16; ++i) {
            pv[i] = run;
            run += wS[(16 * ck + i) * TQ + cq];
        }
        scanP[ck * 32 + cq] = run;      // bank = cq: conflict-free write
        __syncthreads();
        float offs = 0.f;
#pragma unroll
        for (int j = 0; j < 15; ++j)
            if (j < ck) offs += scanP[j * 32 + cq];   // broadcast reads
#pragma unroll
        for (int i = 0; i < 16; ++i)
            wS[(16 * ck + i) * TQ + cq] = offs + pv[i];
        if (ck == 15) wS[NP * TQ + cq] = offs + run;  // grand total row
    }
    __syncthreads();

    // phase C1: grp + size cost for all 8 outputs into registers (prefix lookups)
    const int qoC = t & 31;             // lane-fast -> conflict-free banks
    const int g4A = (t >> 5) * 4;       // rep 0 groups
    const int g4B = g4A + 64;           // rep 1 groups
    float resA[4], resB[4];
    {
        const float sl = slG[qoC], pz = szG[qoC];
#pragma unroll
        for (int rep = 0; rep < 2; ++rep) {
            float* res = rep ? resB : resA;
            const int g4 = rep ? g4B : g4A;
#pragma unroll
            for (int j = 0; j < 4; ++j) {
                const int g  = g4 + j;
                const int cs = cntS[g];
                const int m  = cs >> 16;
                const int st = cs & 0xffff;
                const float ms = wS[(st + m) * TQ + qoC] - wS[st * TQ + qoC];
                const float mf  = (float)m;
                const float nmf = fmaxf((float)(NP - m), 1.f);
                float grp = ms - sl / nmf;     // = -mem/m - (sl-ml)/nm
                float szc = fabsf(pz - mf) * (1.f / (float)NP);
                if (m == 0) { grp = BIGC; szc = BIGC; }
                res[j] = grp + szc;
            }
        }
    }
    __syncthreads();   // all prefix reads done -> wS storage may be reused

    // phase C2: fill predAct tile into the wS region (stride 129, conflict-free)
#pragma unroll
    for (int k = 0; k < 4; ++k) {
        const int r = wv + 8 * k;
        pTile[r * PTS + ln]      = pa0[k];   // bank (r+ln)%32: 2-way max, free
        pTile[r * PTS + 64 + ln] = pa1[k];
    }
    __syncthreads();

    // phase C3: activity term + store
    {
        const float la = lseAct[qoC];
#pragma unroll
        for (int rep = 0; rep < 2; ++rep) {
            float* res = rep ? resB : resA;
            const int g4 = rep ? g4B : g4A;
#pragma unroll
            for (int j = 0; j < 4; ++j) {
                const float av = pTile[qoC * PTS + aidS[g4 + j]];   // LDS gather, conflict-free
                res[j] += la - av;
            }
            *(float4*)(out + ((size_t)(b * NQ + q0 + qoC)) * NG + g4) = *(float4*)res;
        }
    }
}

extern "C" void kernel_launch(void* const* d_in, const int* in_sizes, int n_in,
                              void* d_out, int out_size, void* d_ws, size_t ws_size,
                              hipStream_t stream) {
    const float* predAct = (const float*)d_in[0];
    const float* att     = (const float*)d_in[1];
    const int*   actIds  = (const int*)d_in[2];
    const int*   grpIds  = (const int*)d_in[3];
    float*       out     = (float*)d_out;
    float*       lse     = (float*)d_ws;

    lse_kernel<<<(BS * NP) / 8, 512, 0, stream>>>(att, lse);
    cost_kernel<<<BS * (NQ / TQ), 512, 0, stream>>>(predAct, att, actIds, grpIds, lse, out);
}